// Round 12
// baseline (599.290 us; speedup 1.0000x reference)
//
#include <hip/hip_runtime.h>
#include <math.h>

static constexpr int Nn  = 20000;
static constexpr int Ne  = 320000;
static constexpr int DIN = 128;
static constexpr int DOUTc = 10;
static constexpr int Hc  = 1024;
static constexpr int HMc = 256;
static constexpr float EPSc = 1e-5f;
static constexpr int NB_SCAN = (Nn + 255) / 256;   // 79

typedef __bf16 bf16_t;
typedef __bf16 bf16x8 __attribute__((ext_vector_type(8)));
typedef __bf16 bf16x4 __attribute__((ext_vector_type(4)));
typedef float  f32x4  __attribute__((ext_vector_type(4)));

__device__ __forceinline__ void gload_lds16(const bf16_t* g, bf16_t* lds) {
    __builtin_amdgcn_global_load_lds(
        (const __attribute__((address_space(1))) void*)g,
        (__attribute__((address_space(3))) void*)lds, 16, 0, 0);
}

// ---------------- init: deg=1, cnt=0, stats=0 ----------------
__global__ __launch_bounds__(256)
void deg_init_k(float* __restrict__ deg, int* __restrict__ cnt, float* __restrict__ stats)
{
    int i = blockIdx.x * 256 + threadIdx.x;
    if (i < Nn) { deg[i] = 1.0f; cnt[i] = 0; }     // self-loop weight 1
    if (i < 4 * Hc) stats[i] = 0.f;
}

__global__ __launch_bounds__(256)
void deg_edge_k(const float* __restrict__ w, const int* __restrict__ dstv,
                float* __restrict__ deg, int* __restrict__ cnt) {
    int e = blockIdx.x * 256 + threadIdx.x;
    if (e < Ne) {
        int d = dstv[e];
        atomicAdd(&deg[d], w[e]);
        atomicAdd(&cnt[d], 1);
    }
}

// ---------------- 3-kernel block scan: cnt -> row_ptr/cursor (A finalizes dinv) ----------------
__global__ __launch_bounds__(256)
void scanA_k(const int* __restrict__ cnt, int* __restrict__ row_ptr, int* __restrict__ blk,
             float* __restrict__ deg)
{
    __shared__ int wsum[4];
    int b = blockIdx.x, tid = threadIdx.x, lane = tid & 63, wv = tid >> 6;
    int i = b * 256 + tid;
    if (i < Nn) deg[i] = rsqrtf(deg[i]);           // deg >= 1 always -> dinv
    int v = (i < Nn) ? cnt[i] : 0;
    int s = v;
    #pragma unroll
    for (int off = 1; off < 64; off <<= 1) {
        int t = __shfl_up(s, off, 64);
        if (lane >= off) s += t;
    }
    if (lane == 63) wsum[wv] = s;
    __syncthreads();
    int wo = 0;
    #pragma unroll
    for (int k = 0; k < 4; ++k) if (k < wv) wo += wsum[k];
    if (i < Nn) row_ptr[i] = wo + s - v;           // block-local exclusive
    if (tid == 255) blk[b] = wo + s;               // block total
}

__global__ __launch_bounds__(128)
void scanB_k(int* __restrict__ blk)                // NB_SCAN <= 128
{
    __shared__ int w0;
    int tid = threadIdx.x, lane = tid & 63, wv = tid >> 6;
    int v = (tid < NB_SCAN) ? blk[tid] : 0;
    int s = v;
    #pragma unroll
    for (int off = 1; off < 64; off <<= 1) {
        int t = __shfl_up(s, off, 64);
        if (lane >= off) s += t;
    }
    if (tid == 63) w0 = s;
    __syncthreads();
    int excl = s - v + (wv ? w0 : 0);
    if (tid < NB_SCAN) blk[tid] = excl;
}

__global__ __launch_bounds__(256)
void scanC_k(int* __restrict__ row_ptr, const int* __restrict__ blk, int* __restrict__ cursor)
{
    int b = blockIdx.x;
    int i = b * 256 + threadIdx.x;
    if (i < Nn) {
        int r = row_ptr[i] + blk[b];
        row_ptr[i] = r;
        cursor[i]  = r;
    }
    if (i == 0) row_ptr[Nn] = Ne;
}

// ---------------- CSR fill (coeff precomputed) ----------------
__global__ __launch_bounds__(256)
void csr_fill_k(const int* __restrict__ srcv, const int* __restrict__ dstv,
                const float* __restrict__ w, const float* __restrict__ dinv,
                int* __restrict__ cursor, int* __restrict__ csr_src,
                float* __restrict__ csr_coeff)
{
    int e = blockIdx.x * 256 + threadIdx.x;
    if (e >= Ne) return;
    int s = srcv[e], d = dstv[e];
    int pos = atomicAdd(&cursor[d], 1);
    csr_src[pos]   = s;
    csr_coeff[pos] = dinv[s] * w[e] * dinv[d];
}

// ---------------- gather SpMM over x (128-dim), panel + 4x unrolled ----------------
__global__ __launch_bounds__(256)
void spmm_x_k(const bf16x8* __restrict__ x8, const int* __restrict__ row_ptr,
              const int* __restrict__ csr_src, const float* __restrict__ csr_coeff,
              const float* __restrict__ dinv, bf16x8* __restrict__ out8)
{
    int panel = blockIdx.x & 3;
    int node  = (blockIdx.x >> 2) * 64 + (threadIdx.x >> 2);
    if (node >= Nn) return;
    int f = (threadIdx.x & 3) + panel * 4;
    float c = dinv[node]; c = c * c;
    bf16x8 hv = x8[(size_t)node * 16 + f];
    float acc[8];
    #pragma unroll
    for (int i = 0; i < 8; ++i) acc[i] = c * (float)hv[i];
    int beg = row_ptr[node], end = row_ptr[node + 1];
    int j = beg;
    for (; j + 4 <= end; j += 4) {
        int   s0 = csr_src[j + 0], s1 = csr_src[j + 1];
        int   s2 = csr_src[j + 2], s3 = csr_src[j + 3];
        float c0 = csr_coeff[j + 0], c1 = csr_coeff[j + 1];
        float c2 = csr_coeff[j + 2], c3 = csr_coeff[j + 3];
        bf16x8 v0 = x8[(size_t)s0 * 16 + f];
        bf16x8 v1 = x8[(size_t)s1 * 16 + f];
        bf16x8 v2 = x8[(size_t)s2 * 16 + f];
        bf16x8 v3 = x8[(size_t)s3 * 16 + f];
        #pragma unroll
        for (int i = 0; i < 8; ++i) {
            acc[i] = fmaf(c0, (float)v0[i], acc[i]);
            acc[i] = fmaf(c1, (float)v1[i], acc[i]);
            acc[i] = fmaf(c2, (float)v2[i], acc[i]);
            acc[i] = fmaf(c3, (float)v3[i], acc[i]);
        }
    }
    for (; j < end; ++j) {
        int   s  = csr_src[j];
        float cf = csr_coeff[j];
        bf16x8 v = x8[(size_t)s * 16 + f];
        #pragma unroll
        for (int i = 0; i < 8; ++i) acc[i] = fmaf(cf, (float)v[i], acc[i]);
    }
    bf16x8 o;
    #pragma unroll
    for (int i = 0; i < 8; ++i) o[i] = (bf16_t)acc[i];
    out8[(size_t)node * 16 + f] = o;
}

// ---------------- gather SpMM over h (1024-dim), panel + 8x unrolled, fused BN stats ----------------
// 8 panels x 128 feats; 16 nodes/block, 16 lanes/node. Stats: wave shfl-reduce over
// 4 nodes -> LDS cross-wave -> one atomicAdd per column per block.
__global__ __launch_bounds__(256)
void spmm_h_k(const bf16x8* __restrict__ h8, const int* __restrict__ row_ptr,
              const int* __restrict__ csr_src, const float* __restrict__ csr_coeff,
              const float* __restrict__ dinv, bf16x8* __restrict__ out8,
              float* __restrict__ s1g, float* __restrict__ s2g)
{
    __shared__ float smS[4][16][8];
    __shared__ float smQ[4][16][8];
    int panel = blockIdx.x & 7;
    int node  = (blockIdx.x >> 3) * 16 + (threadIdx.x >> 4);   // grid = 8*1250 exact
    int fu    = threadIdx.x & 15;
    int f     = fu + panel * 16;
    float c = dinv[node]; c = c * c;
    bf16x8 hv = h8[(size_t)node * 128 + f];
    float acc[8];
    #pragma unroll
    for (int i = 0; i < 8; ++i) acc[i] = c * (float)hv[i];
    int beg = row_ptr[node], end = row_ptr[node + 1];
    int j = beg;
    for (; j + 8 <= end; j += 8) {                 // 8 independent gathers in flight
        int   s0 = csr_src[j + 0], s1 = csr_src[j + 1];
        int   s2 = csr_src[j + 2], s3 = csr_src[j + 3];
        int   s4 = csr_src[j + 4], s5 = csr_src[j + 5];
        int   s6 = csr_src[j + 6], s7 = csr_src[j + 7];
        float c0 = csr_coeff[j + 0], c1 = csr_coeff[j + 1];
        float c2 = csr_coeff[j + 2], c3 = csr_coeff[j + 3];
        float c4 = csr_coeff[j + 4], c5 = csr_coeff[j + 5];
        float c6 = csr_coeff[j + 6], c7 = csr_coeff[j + 7];
        bf16x8 v0 = h8[(size_t)s0 * 128 + f];
        bf16x8 v1 = h8[(size_t)s1 * 128 + f];
        bf16x8 v2 = h8[(size_t)s2 * 128 + f];
        bf16x8 v3 = h8[(size_t)s3 * 128 + f];
        bf16x8 v4 = h8[(size_t)s4 * 128 + f];
        bf16x8 v5 = h8[(size_t)s5 * 128 + f];
        bf16x8 v6 = h8[(size_t)s6 * 128 + f];
        bf16x8 v7 = h8[(size_t)s7 * 128 + f];
        #pragma unroll
        for (int i = 0; i < 8; ++i) {
            acc[i] = fmaf(c0, (float)v0[i], acc[i]);
            acc[i] = fmaf(c1, (float)v1[i], acc[i]);
            acc[i] = fmaf(c2, (float)v2[i], acc[i]);
            acc[i] = fmaf(c3, (float)v3[i], acc[i]);
            acc[i] = fmaf(c4, (float)v4[i], acc[i]);
            acc[i] = fmaf(c5, (float)v5[i], acc[i]);
            acc[i] = fmaf(c6, (float)v6[i], acc[i]);
            acc[i] = fmaf(c7, (float)v7[i], acc[i]);
        }
    }
    for (; j + 4 <= end; j += 4) {
        int   s0 = csr_src[j + 0], s1 = csr_src[j + 1];
        int   s2 = csr_src[j + 2], s3 = csr_src[j + 3];
        float c0 = csr_coeff[j + 0], c1 = csr_coeff[j + 1];
        float c2 = csr_coeff[j + 2], c3 = csr_coeff[j + 3];
        bf16x8 v0 = h8[(size_t)s0 * 128 + f];
        bf16x8 v1 = h8[(size_t)s1 * 128 + f];
        bf16x8 v2 = h8[(size_t)s2 * 128 + f];
        bf16x8 v3 = h8[(size_t)s3 * 128 + f];
        #pragma unroll
        for (int i = 0; i < 8; ++i) {
            acc[i] = fmaf(c0, (float)v0[i], acc[i]);
            acc[i] = fmaf(c1, (float)v1[i], acc[i]);
            acc[i] = fmaf(c2, (float)v2[i], acc[i]);
            acc[i] = fmaf(c3, (float)v3[i], acc[i]);
        }
    }
    for (; j < end; ++j) {
        int   s  = csr_src[j];
        float cf = csr_coeff[j];
        bf16x8 v = h8[(size_t)s * 128 + f];
        #pragma unroll
        for (int i = 0; i < 8; ++i) acc[i] = fmaf(cf, (float)v[i], acc[i]);
    }
    bf16x8 o;
    #pragma unroll
    for (int i = 0; i < 8; ++i) o[i] = (bf16_t)acc[i];
    out8[(size_t)node * 128 + f] = o;

    // fused BN stats (fp32 pre-rounding values)
    int lane = threadIdx.x & 63, wv = threadIdx.x >> 6;
    float ps[8], pq[8];
    #pragma unroll
    for (int i = 0; i < 8; ++i) { ps[i] = acc[i]; pq[i] = acc[i] * acc[i]; }
    #pragma unroll
    for (int i = 0; i < 8; ++i) {
        ps[i] += __shfl_down(ps[i], 32, 64); ps[i] += __shfl_down(ps[i], 16, 64);
        pq[i] += __shfl_down(pq[i], 32, 64); pq[i] += __shfl_down(pq[i], 16, 64);
    }
    if (lane < 16) {
        #pragma unroll
        for (int i = 0; i < 8; ++i) { smS[wv][lane][i] = ps[i]; smQ[wv][lane][i] = pq[i]; }
    }
    __syncthreads();
    if (threadIdx.x < 16) {
        int u = threadIdx.x;
        #pragma unroll
        for (int i = 0; i < 8; ++i) {
            float a = smS[0][u][i] + smS[1][u][i] + smS[2][u][i] + smS[3][u][i];
            float b = smQ[0][u][i] + smQ[1][u][i] + smQ[2][u][i] + smQ[3][u][i];
            int col = (u + panel * 16) * 8 + i;
            atomicAdd(&s1g[col], a);
            atomicAdd(&s2g[col], b);
        }
    }
}

// ---------------- merged weight transpose + convert (3 matrices, one dispatch) ----------------
__global__ __launch_bounds__(256)
void transpose_all_k(const float* __restrict__ W1, const float* __restrict__ W2,
                     const float* __restrict__ Wl1, bf16_t* __restrict__ W1t,
                     bf16_t* __restrict__ W2t, bf16_t* __restrict__ Wl1t)
{
    __shared__ float tile[32][33];
    int b = blockIdx.x;
    const float* W; bf16_t* Wt; int R, C, bx, by;
    if (b < 128)       { W = W1;  Wt = W1t;  R = DIN; C = Hc;  int t = b;        bx = (t & 31) * 32; by = (t >> 5) * 32; }
    else if (b < 1152) { W = W2;  Wt = W2t;  R = Hc;  C = Hc;  int t = b - 128;  bx = (t & 31) * 32; by = (t >> 5) * 32; }
    else               { W = Wl1; Wt = Wl1t; R = Hc;  C = HMc; int t = b - 1152; bx = (t & 7) * 32;  by = (t >> 3) * 32; }
    int tx = threadIdx.x & 31, ty = threadIdx.x >> 5;  // ty 0..7
    #pragma unroll
    for (int p = 0; p < 32; p += 8)
        tile[ty + p][tx] = W[(size_t)(by + ty + p) * C + bx + tx];
    __syncthreads();
    #pragma unroll
    for (int p = 0; p < 32; p += 8)
        Wt[(size_t)(bx + ty + p) * R + by + tx] = (bf16_t)tile[tx][ty + p];
}

// ---------------- fp32 -> bf16 convert (x) ----------------
__global__ __launch_bounds__(256)
void cvt_bf16_k(const float4* __restrict__ in, bf16x4* __restrict__ out, int n4)
{
    int i = blockIdx.x * 256 + threadIdx.x;
    if (i >= n4) return;
    float4 v = in[i];
    bf16x4 o = { (bf16_t)v.x, (bf16_t)v.y, (bf16_t)v.z, (bf16_t)v.w };
    out[i] = o;
}

// ---------------- bf16 MFMA GEMM: C[M x NC] = A[M x KD] @ Bt[NC x KD]^T ----------------
template<int NC, int KD, bool BIAS, bool RELU, bool OUTBF, bool STATS>
__global__ __launch_bounds__(256)
void gemm_bf16_k(const bf16_t* __restrict__ A, const bf16_t* __restrict__ Bt,
                 const float* __restrict__ bias, void* __restrict__ Cv, int M,
                 float* __restrict__ s1g, float* __restrict__ s2g)
{
    __shared__ __align__(16) bf16_t Asm[128 * 32];
    __shared__ __align__(16) bf16_t Bsm[128 * 32];
    const int tid  = threadIdx.x;
    const int w    = tid >> 6;
    const int lane = tid & 63;
    const int bm = blockIdx.y * 128, bn = blockIdx.x * 128;
    const int l15 = lane & 15, quad = lane >> 4;
    const int wm = (w & 1) * 64, wn = (w >> 1) * 64;
    const int swz = quad ^ ((l15 >> 1) & 3);

    const int srow = lane >> 2;
    const int scol = 8 * ((lane & 3) ^ ((lane >> 3) & 3));
    const int c0 = w * 32;
    int ga0 = bm + c0 + srow;       if (ga0 >= M) ga0 = M - 1;
    int ga1 = bm + c0 + 16 + srow;  if (ga1 >= M) ga1 = M - 1;
    const bf16_t* gA0 = A + (size_t)ga0 * KD + scol;
    const bf16_t* gA1 = A + (size_t)ga1 * KD + scol;
    const bf16_t* gB0 = Bt + (size_t)(bn + c0 + srow) * KD + scol;
    const bf16_t* gB1 = gB0 + (size_t)16 * KD;
    bf16_t* lA0 = Asm + (c0 +  0) * 32;
    bf16_t* lA1 = Asm + (c0 + 16) * 32;
    bf16_t* lB0 = Bsm + (c0 +  0) * 32;
    bf16_t* lB1 = Bsm + (c0 + 16) * 32;

    const bf16_t* pA = Asm + (wm + l15) * 32 + swz * 8;
    const bf16_t* pB = Bsm + (wn + l15) * 32 + swz * 8;

    f32x4 acc[4][4] = {};

    for (int k0 = 0; k0 < KD; k0 += 32) {
        gload_lds16(gA0 + k0, lA0);
        gload_lds16(gA1 + k0, lA1);
        gload_lds16(gB0 + k0, lB0);
        gload_lds16(gB1 + k0, lB1);
        __syncthreads();
        bf16x8 af[4], bfr[4];
        #pragma unroll
        for (int t = 0; t < 4; ++t) {
            af[t]  = *(const bf16x8*)(pA + t * 16 * 32);
            bfr[t] = *(const bf16x8*)(pB + t * 16 * 32);
        }
        #pragma unroll
        for (int mt = 0; mt < 4; ++mt)
            #pragma unroll
            for (int nt = 0; nt < 4; ++nt)
                acc[mt][nt] = __builtin_amdgcn_mfma_f32_16x16x32_bf16(
                    af[mt], bfr[nt], acc[mt][nt], 0, 0, 0);
        __syncthreads();
    }

    #pragma unroll
    for (int mt = 0; mt < 4; ++mt) {
        #pragma unroll
        for (int r = 0; r < 4; ++r) {
            int row = bm + wm + mt * 16 + quad * 4 + r;
            if (row >= M) continue;
            #pragma unroll
            for (int nt = 0; nt < 4; ++nt) {
                int col = bn + wn + nt * 16 + l15;
                float v = acc[mt][nt][r];
                if (BIAS) v += bias[col];
                if (RELU) v = fmaxf(v, 0.f);
                if (OUTBF) ((bf16_t*)Cv)[(size_t)row * NC + col] = (bf16_t)v;
                else       ((float*)Cv)[(size_t)row * NC + col] = v;
            }
        }
    }

    if (STATS) {
        #pragma unroll
        for (int nt = 0; nt < 4; ++nt) {
            float ps = 0.f, pq = 0.f;
            #pragma unroll
            for (int mt = 0; mt < 4; ++mt)
                #pragma unroll
                for (int r = 0; r < 4; ++r) {
                    int row = bm + wm + mt * 16 + quad * 4 + r;
                    if (row < M) {
                        float v = acc[mt][nt][r];
                        ps += v;
                        pq = fmaf(v, v, pq);
                    }
                }
            ps += __shfl_down(ps, 32, 64); ps += __shfl_down(ps, 16, 64);
            pq += __shfl_down(pq, 32, 64); pq += __shfl_down(pq, 16, 64);
            if (quad == 0) {
                int col = bn + wn + nt * 16 + l15;
                atomicAdd(&s1g[col], ps);
                atomicAdd(&s2g[col], pq);
            }
        }
    }
}

// ---------------- batchnorm apply (fused finalize) ----------------
__global__ __launch_bounds__(256)
void bn_apply_k(const bf16x8* __restrict__ x8, const float* __restrict__ s1,
                const float* __restrict__ s2, const float* __restrict__ g,
                const float* __restrict__ beta, bf16x8* __restrict__ out8)
{
    int idx = blockIdx.x * 256 + threadIdx.x;      // grid = Nn*Hc/8/256 = 10000
    int c8 = (idx & 127) << 3;
    bf16x8 v = x8[idx];
    bf16x8 o;
    #pragma unroll
    for (int i = 0; i < 8; ++i) {
        int c = c8 + i;
        float mean = s1[c] * (1.0f / Nn);
        float var  = s2[c] * (1.0f / Nn) - mean * mean;
        float sc = g[c] * rsqrtf(var + EPSc);
        float sh = beta[c] - mean * sc;
        o[i] = (bf16_t)fmaxf(fmaf((float)v[i], sc, sh), 0.f);
    }
    out8[idx] = o;
}

// ---------------- head: out = log_softmax(z @ Wl2 + bl2), z in bf16 ----------------
__global__ __launch_bounds__(256)
void head_k(const bf16_t* __restrict__ z, const float* __restrict__ Wl2,
            const float* __restrict__ bl2, float* __restrict__ out)
{
    int wave = threadIdx.x >> 6;
    int lane = threadIdx.x & 63;
    int node = blockIdx.x * 4 + wave;              // grid = Nn/4 exact
    const bf16x4 zv = *(const bf16x4*)(z + (size_t)node * HMc + lane * 4);
    float p[DOUTc];
    #pragma unroll
    for (int j = 0; j < DOUTc; ++j) p[j] = 0.f;
    const float zz[4] = {(float)zv[0], (float)zv[1], (float)zv[2], (float)zv[3]};
    #pragma unroll
    for (int i = 0; i < 4; ++i) {
        int k = lane * 4 + i;
        const float* wrow = Wl2 + (size_t)k * DOUTc;
        #pragma unroll
        for (int j = 0; j < DOUTc; ++j) p[j] = fmaf(zz[i], wrow[j], p[j]);
    }
    #pragma unroll
    for (int j = 0; j < DOUTc; ++j) {
        #pragma unroll
        for (int off = 32; off > 0; off >>= 1) p[j] += __shfl_down(p[j], off, 64);
    }
    if (lane == 0) {
        float v[DOUTc];
        float m = -1e30f;
        #pragma unroll
        for (int j = 0; j < DOUTc; ++j) { v[j] = p[j] + bl2[j]; m = fmaxf(m, v[j]); }
        float s = 0.f;
        #pragma unroll
        for (int j = 0; j < DOUTc; ++j) s += expf(v[j] - m);
        float ls = logf(s) + m;
        #pragma unroll
        for (int j = 0; j < DOUTc; ++j) out[(size_t)node * DOUTc + j] = v[j] - ls;
    }
}

// ---------------- launch ----------------
extern "C" void kernel_launch(void* const* d_in, const int* in_sizes, int n_in,
                              void* d_out, int out_size, void* d_ws, size_t ws_size,
                              hipStream_t stream)
{
    (void)in_sizes; (void)n_in; (void)out_size; (void)ws_size;
    const float* x    = (const float*)d_in[0];
    const int*   ei   = (const int*)d_in[1];
    const float* ew   = (const float*)d_in[2];
    const float* W1   = (const float*)d_in[3];
    // b1 = d_in[4]: cancels under batchnorm mean-subtraction
    const float* gam1 = (const float*)d_in[5];
    const float* bet1 = (const float*)d_in[6];
    const float* W2   = (const float*)d_in[7];
    // b2 = d_in[8]: cancels
    const float* gam2 = (const float*)d_in[9];
    const float* bet2 = (const float*)d_in[10];
    const float* Wl1  = (const float*)d_in[11];
    const float* bl1  = (const float*)d_in[12];
    const float* Wl2  = (const float*)d_in[13];
    const float* bl2  = (const float*)d_in[14];
    float* out = (float*)d_out;

    float* dinv  = (float*)d_ws;                   // Nn
    float* stats = dinv + Nn;                      // 4*Hc: s1a,s2a,s1b,s2b
    float* s1a = stats, *s2a = stats + Hc, *s1b = stats + 2 * Hc, *s2b = stats + 3 * Hc;
    int*   cnt      = (int*)(stats + 4 * Hc);      // Nn
    int*   row_ptr  = cnt + Nn;                    // Nn+16
    int*   cursor   = row_ptr + Nn + 16;           // Nn
    int*   blk      = cursor + Nn;                 // NB_SCAN (+pad)
    int*   csr_src  = blk + 128;                   // Ne
    float* csr_coef = (float*)(csr_src + Ne);      // Ne
    bf16_t* xb    = (bf16_t*)(csr_coef + Ne);      // Nn*DIN  (16B aligned)
    bf16_t* xagg  = xb + (size_t)Nn * DIN;         // Nn*DIN  (aggregated x)
    bf16_t* hgem  = xagg + (size_t)Nn * DIN;       // Nn*Hc   ping
    bf16_t* hbf   = hgem + (size_t)Nn * Hc;        // Nn*Hc   pong
    bf16_t* zhead = hbf + (size_t)Nn * Hc;         // Nn*HMc  (head GEMM out, bf16)
    bf16_t* W1t   = zhead + (size_t)Nn * HMc;      // Hc*DIN  (= W1^T)
    bf16_t* W2t   = W1t + (size_t)Hc * DIN;        // Hc*Hc   (= W2^T)
    bf16_t* Wl1t  = W2t + (size_t)Hc * Hc;         // HMc*Hc  (= Wl1^T)

    const int* srcv = ei;
    const int* dstv = ei + Ne;

    // ---- one-time per launch: dinv + CSR + bf16 weights/x ----
    deg_init_k<<<NB_SCAN, 256, 0, stream>>>(dinv, cnt, stats);
    deg_edge_k<<<(Ne + 255) / 256, 256, 0, stream>>>(ew, dstv, dinv, cnt);
    scanA_k<<<NB_SCAN, 256, 0, stream>>>(cnt, row_ptr, blk, dinv);
    scanB_k<<<1, 128, 0, stream>>>(blk);
    scanC_k<<<NB_SCAN, 256, 0, stream>>>(row_ptr, blk, cursor);
    csr_fill_k<<<(Ne + 255) / 256, 256, 0, stream>>>(srcv, dstv, ew, dinv, cursor,
                                                     csr_src, csr_coef);
    transpose_all_k<<<1408, 256, 0, stream>>>(W1, W2, Wl1, W1t, W2t, Wl1t);
    cvt_bf16_k<<<(Nn * DIN / 4 + 255) / 256, 256, 0, stream>>>(
        (const float4*)x, (bf16x4*)xb, Nn * DIN / 4);

    const int MB = (Nn + 127) / 128;               // 157 row-blocks

    // layer 1:  (A X) W1  — aggregate first (128-dim), then GEMM with fused BN stats
    spmm_x_k<<<4 * ((Nn + 63) / 64), 256, 0, stream>>>(
        (const bf16x8*)xb, row_ptr, csr_src, csr_coef, dinv, (bf16x8*)xagg);
    gemm_bf16_k<Hc, DIN, false, false, true, true><<<dim3(Hc / 128, MB), 256, 0, stream>>>(
        xagg, W1t, nullptr, hgem, Nn, s1a, s2a);
    bn_apply_k<<<Nn * Hc / 8 / 256, 256, 0, stream>>>(
        (const bf16x8*)hgem, s1a, s2a, gam1, bet1, (bf16x8*)hbf);

    // layer 2:  GEMM, aggregate (1024-dim, panel-partitioned, fused BN stats), BN
    gemm_bf16_k<Hc, Hc, false, false, true, false><<<dim3(Hc / 128, MB), 256, 0, stream>>>(
        hbf, W2t, nullptr, hgem, Nn, nullptr, nullptr);
    spmm_h_k<<<8 * (Nn / 16), 256, 0, stream>>>(
        (const bf16x8*)hgem, row_ptr, csr_src, csr_coef, dinv, (bf16x8*)hbf, s1b, s2b);
    bn_apply_k<<<Nn * Hc / 8 / 256, 256, 0, stream>>>(
        (const bf16x8*)hbf, s1b, s2b, gam2, bet2, (bf16x8*)hgem);

    // MLP head: z = relu(h @ Wl1 + bl1) (bf16 out), then fused GEMM+log_softmax
    gemm_bf16_k<HMc, Hc, true, true, true, false><<<dim3(HMc / 128, MB), 256, 0, stream>>>(
        hgem, Wl1t, bl1, zhead, Nn, nullptr, nullptr);
    head_k<<<Nn / 4, 256, 0, stream>>>(zhead, Wl2, bl2, out);
}

// Round 13
// 436.137 us; speedup vs baseline: 1.3741x; 1.3741x over previous
//
#include <hip/hip_runtime.h>
#include <math.h>

static constexpr int Nn  = 20000;
static constexpr int Ne  = 320000;
static constexpr int DIN = 128;
static constexpr int DOUTc = 10;
static constexpr int Hc  = 1024;
static constexpr int HMc = 256;
static constexpr float EPSc = 1e-5f;
static constexpr int NB_SCAN = (Nn + 255) / 256;   // 79

typedef __bf16 bf16_t;
typedef __bf16 bf16x8 __attribute__((ext_vector_type(8)));
typedef __bf16 bf16x4 __attribute__((ext_vector_type(4)));
typedef float  f32x4  __attribute__((ext_vector_type(4)));

__device__ __forceinline__ void gload_lds16(const bf16_t* g, bf16_t* lds) {
    __builtin_amdgcn_global_load_lds(
        (const __attribute__((address_space(1))) void*)g,
        (__attribute__((address_space(3))) void*)lds, 16, 0, 0);
}

// ---------------- init: deg=1, cnt=0, stats=0 ----------------
__global__ __launch_bounds__(256)
void deg_init_k(float* __restrict__ deg, int* __restrict__ cnt, float* __restrict__ stats)
{
    int i = blockIdx.x * 256 + threadIdx.x;
    if (i < Nn) { deg[i] = 1.0f; cnt[i] = 0; }     // self-loop weight 1
    if (i < 4 * Hc) stats[i] = 0.f;
}

__global__ __launch_bounds__(256)
void deg_edge_k(const float* __restrict__ w, const int* __restrict__ dstv,
                float* __restrict__ deg, int* __restrict__ cnt) {
    int e = blockIdx.x * 256 + threadIdx.x;
    if (e < Ne) {
        int d = dstv[e];
        atomicAdd(&deg[d], w[e]);
        atomicAdd(&cnt[d], 1);
    }
}

// ---------------- 3-kernel block scan: cnt -> row_ptr/cursor (A finalizes dinv) ----------------
__global__ __launch_bounds__(256)
void scanA_k(const int* __restrict__ cnt, int* __restrict__ row_ptr, int* __restrict__ blk,
             float* __restrict__ deg)
{
    __shared__ int wsum[4];
    int b = blockIdx.x, tid = threadIdx.x, lane = tid & 63, wv = tid >> 6;
    int i = b * 256 + tid;
    if (i < Nn) deg[i] = rsqrtf(deg[i]);           // deg >= 1 always -> dinv
    int v = (i < Nn) ? cnt[i] : 0;
    int s = v;
    #pragma unroll
    for (int off = 1; off < 64; off <<= 1) {
        int t = __shfl_up(s, off, 64);
        if (lane >= off) s += t;
    }
    if (lane == 63) wsum[wv] = s;
    __syncthreads();
    int wo = 0;
    #pragma unroll
    for (int k = 0; k < 4; ++k) if (k < wv) wo += wsum[k];
    if (i < Nn) row_ptr[i] = wo + s - v;           // block-local exclusive
    if (tid == 255) blk[b] = wo + s;               // block total
}

__global__ __launch_bounds__(128)
void scanB_k(int* __restrict__ blk)                // NB_SCAN <= 128
{
    __shared__ int w0;
    int tid = threadIdx.x, lane = tid & 63, wv = tid >> 6;
    int v = (tid < NB_SCAN) ? blk[tid] : 0;
    int s = v;
    #pragma unroll
    for (int off = 1; off < 64; off <<= 1) {
        int t = __shfl_up(s, off, 64);
        if (lane >= off) s += t;
    }
    if (tid == 63) w0 = s;
    __syncthreads();
    int excl = s - v + (wv ? w0 : 0);
    if (tid < NB_SCAN) blk[tid] = excl;
}

__global__ __launch_bounds__(256)
void scanC_k(int* __restrict__ row_ptr, const int* __restrict__ blk, int* __restrict__ cursor)
{
    int b = blockIdx.x;
    int i = b * 256 + threadIdx.x;
    if (i < Nn) {
        int r = row_ptr[i] + blk[b];
        row_ptr[i] = r;
        cursor[i]  = r;
    }
    if (i == 0) row_ptr[Nn] = Ne;
}

// ---------------- CSR fill (coeff precomputed) ----------------
__global__ __launch_bounds__(256)
void csr_fill_k(const int* __restrict__ srcv, const int* __restrict__ dstv,
                const float* __restrict__ w, const float* __restrict__ dinv,
                int* __restrict__ cursor, int* __restrict__ csr_src,
                float* __restrict__ csr_coeff)
{
    int e = blockIdx.x * 256 + threadIdx.x;
    if (e >= Ne) return;
    int s = srcv[e], d = dstv[e];
    int pos = atomicAdd(&cursor[d], 1);
    csr_src[pos]   = s;
    csr_coeff[pos] = dinv[s] * w[e] * dinv[d];
}

// ---------------- gather SpMM over x (128-dim), panel + 4x unrolled ----------------
__global__ __launch_bounds__(256)
void spmm_x_k(const bf16x8* __restrict__ x8, const int* __restrict__ row_ptr,
              const int* __restrict__ csr_src, const float* __restrict__ csr_coeff,
              const float* __restrict__ dinv, bf16x8* __restrict__ out8)
{
    int panel = blockIdx.x & 3;
    int node  = (blockIdx.x >> 2) * 64 + (threadIdx.x >> 2);
    if (node >= Nn) return;
    int f = (threadIdx.x & 3) + panel * 4;
    float c = dinv[node]; c = c * c;
    bf16x8 hv = x8[(size_t)node * 16 + f];
    float acc[8];
    #pragma unroll
    for (int i = 0; i < 8; ++i) acc[i] = c * (float)hv[i];
    int beg = row_ptr[node], end = row_ptr[node + 1];
    int j = beg;
    for (; j + 4 <= end; j += 4) {
        int   s0 = csr_src[j + 0], s1 = csr_src[j + 1];
        int   s2 = csr_src[j + 2], s3 = csr_src[j + 3];
        float c0 = csr_coeff[j + 0], c1 = csr_coeff[j + 1];
        float c2 = csr_coeff[j + 2], c3 = csr_coeff[j + 3];
        bf16x8 v0 = x8[(size_t)s0 * 16 + f];
        bf16x8 v1 = x8[(size_t)s1 * 16 + f];
        bf16x8 v2 = x8[(size_t)s2 * 16 + f];
        bf16x8 v3 = x8[(size_t)s3 * 16 + f];
        #pragma unroll
        for (int i = 0; i < 8; ++i) {
            acc[i] = fmaf(c0, (float)v0[i], acc[i]);
            acc[i] = fmaf(c1, (float)v1[i], acc[i]);
            acc[i] = fmaf(c2, (float)v2[i], acc[i]);
            acc[i] = fmaf(c3, (float)v3[i], acc[i]);
        }
    }
    for (; j < end; ++j) {
        int   s  = csr_src[j];
        float cf = csr_coeff[j];
        bf16x8 v = x8[(size_t)s * 16 + f];
        #pragma unroll
        for (int i = 0; i < 8; ++i) acc[i] = fmaf(cf, (float)v[i], acc[i]);
    }
    bf16x8 o;
    #pragma unroll
    for (int i = 0; i < 8; ++i) o[i] = (bf16_t)acc[i];
    out8[(size_t)node * 16 + f] = o;
}

// ---------------- gather SpMM over h (1024-dim), panel + 4x unrolled ----------------
// 8 panels x 128 feats; 16 nodes/block, 16 lanes/node. (round-11 proven: 93.5us,
// VGPR 28, occupancy 72% — do NOT fuse stats or widen unroll; both regress occupancy)
__global__ __launch_bounds__(256)
void spmm_h_k(const bf16x8* __restrict__ h8, const int* __restrict__ row_ptr,
              const int* __restrict__ csr_src, const float* __restrict__ csr_coeff,
              const float* __restrict__ dinv, bf16x8* __restrict__ out8)
{
    int panel = blockIdx.x & 7;
    int node  = (blockIdx.x >> 3) * 16 + (threadIdx.x >> 4);   // grid = 8*1250 exact
    int f     = (threadIdx.x & 15) + panel * 16;
    float c = dinv[node]; c = c * c;
    bf16x8 hv = h8[(size_t)node * 128 + f];
    float acc[8];
    #pragma unroll
    for (int i = 0; i < 8; ++i) acc[i] = c * (float)hv[i];
    int beg = row_ptr[node], end = row_ptr[node + 1];
    int j = beg;
    for (; j + 4 <= end; j += 4) {                 // 4 independent gathers in flight
        int   s0 = csr_src[j + 0], s1 = csr_src[j + 1];
        int   s2 = csr_src[j + 2], s3 = csr_src[j + 3];
        float c0 = csr_coeff[j + 0], c1 = csr_coeff[j + 1];
        float c2 = csr_coeff[j + 2], c3 = csr_coeff[j + 3];
        bf16x8 v0 = h8[(size_t)s0 * 128 + f];
        bf16x8 v1 = h8[(size_t)s1 * 128 + f];
        bf16x8 v2 = h8[(size_t)s2 * 128 + f];
        bf16x8 v3 = h8[(size_t)s3 * 128 + f];
        #pragma unroll
        for (int i = 0; i < 8; ++i) {
            acc[i] = fmaf(c0, (float)v0[i], acc[i]);
            acc[i] = fmaf(c1, (float)v1[i], acc[i]);
            acc[i] = fmaf(c2, (float)v2[i], acc[i]);
            acc[i] = fmaf(c3, (float)v3[i], acc[i]);
        }
    }
    for (; j < end; ++j) {
        int   s  = csr_src[j];
        float cf = csr_coeff[j];
        bf16x8 v = h8[(size_t)s * 128 + f];
        #pragma unroll
        for (int i = 0; i < 8; ++i) acc[i] = fmaf(cf, (float)v[i], acc[i]);
    }
    bf16x8 o;
    #pragma unroll
    for (int i = 0; i < 8; ++i) o[i] = (bf16_t)acc[i];
    out8[(size_t)node * 128 + f] = o;
}

// ---------------- merged weight transpose + convert (3 matrices, one dispatch) ----------------
__global__ __launch_bounds__(256)
void transpose_all_k(const float* __restrict__ W1, const float* __restrict__ W2,
                     const float* __restrict__ Wl1, bf16_t* __restrict__ W1t,
                     bf16_t* __restrict__ W2t, bf16_t* __restrict__ Wl1t)
{
    __shared__ float tile[32][33];
    int b = blockIdx.x;
    const float* W; bf16_t* Wt; int R, C, bx, by;
    if (b < 128)       { W = W1;  Wt = W1t;  R = DIN; C = Hc;  int t = b;        bx = (t & 31) * 32; by = (t >> 5) * 32; }
    else if (b < 1152) { W = W2;  Wt = W2t;  R = Hc;  C = Hc;  int t = b - 128;  bx = (t & 31) * 32; by = (t >> 5) * 32; }
    else               { W = Wl1; Wt = Wl1t; R = Hc;  C = HMc; int t = b - 1152; bx = (t & 7) * 32;  by = (t >> 3) * 32; }
    int tx = threadIdx.x & 31, ty = threadIdx.x >> 5;  // ty 0..7
    #pragma unroll
    for (int p = 0; p < 32; p += 8)
        tile[ty + p][tx] = W[(size_t)(by + ty + p) * C + bx + tx];
    __syncthreads();
    #pragma unroll
    for (int p = 0; p < 32; p += 8)
        Wt[(size_t)(bx + ty + p) * R + by + tx] = (bf16_t)tile[tx][ty + p];
}

// ---------------- fp32 -> bf16 convert (x) ----------------
__global__ __launch_bounds__(256)
void cvt_bf16_k(const float4* __restrict__ in, bf16x4* __restrict__ out, int n4)
{
    int i = blockIdx.x * 256 + threadIdx.x;
    if (i >= n4) return;
    float4 v = in[i];
    bf16x4 o = { (bf16_t)v.x, (bf16_t)v.y, (bf16_t)v.z, (bf16_t)v.w };
    out[i] = o;
}

// ---------------- bf16 MFMA GEMM: C[M x NC] = A[M x KD] @ Bt[NC x KD]^T ----------------
template<int NC, int KD, bool BIAS, bool RELU, bool OUTBF, bool STATS>
__global__ __launch_bounds__(256)
void gemm_bf16_k(const bf16_t* __restrict__ A, const bf16_t* __restrict__ Bt,
                 const float* __restrict__ bias, void* __restrict__ Cv, int M,
                 float* __restrict__ s1g, float* __restrict__ s2g)
{
    __shared__ __align__(16) bf16_t Asm[128 * 32];
    __shared__ __align__(16) bf16_t Bsm[128 * 32];
    const int tid  = threadIdx.x;
    const int w    = tid >> 6;
    const int lane = tid & 63;
    const int bm = blockIdx.y * 128, bn = blockIdx.x * 128;
    const int l15 = lane & 15, quad = lane >> 4;
    const int wm = (w & 1) * 64, wn = (w >> 1) * 64;
    const int swz = quad ^ ((l15 >> 1) & 3);

    const int srow = lane >> 2;
    const int scol = 8 * ((lane & 3) ^ ((lane >> 3) & 3));
    const int c0 = w * 32;
    int ga0 = bm + c0 + srow;       if (ga0 >= M) ga0 = M - 1;
    int ga1 = bm + c0 + 16 + srow;  if (ga1 >= M) ga1 = M - 1;
    const bf16_t* gA0 = A + (size_t)ga0 * KD + scol;
    const bf16_t* gA1 = A + (size_t)ga1 * KD + scol;
    const bf16_t* gB0 = Bt + (size_t)(bn + c0 + srow) * KD + scol;
    const bf16_t* gB1 = gB0 + (size_t)16 * KD;
    bf16_t* lA0 = Asm + (c0 +  0) * 32;
    bf16_t* lA1 = Asm + (c0 + 16) * 32;
    bf16_t* lB0 = Bsm + (c0 +  0) * 32;
    bf16_t* lB1 = Bsm + (c0 + 16) * 32;

    const bf16_t* pA = Asm + (wm + l15) * 32 + swz * 8;
    const bf16_t* pB = Bsm + (wn + l15) * 32 + swz * 8;

    f32x4 acc[4][4] = {};

    for (int k0 = 0; k0 < KD; k0 += 32) {
        gload_lds16(gA0 + k0, lA0);
        gload_lds16(gA1 + k0, lA1);
        gload_lds16(gB0 + k0, lB0);
        gload_lds16(gB1 + k0, lB1);
        __syncthreads();
        bf16x8 af[4], bfr[4];
        #pragma unroll
        for (int t = 0; t < 4; ++t) {
            af[t]  = *(const bf16x8*)(pA + t * 16 * 32);
            bfr[t] = *(const bf16x8*)(pB + t * 16 * 32);
        }
        #pragma unroll
        for (int mt = 0; mt < 4; ++mt)
            #pragma unroll
            for (int nt = 0; nt < 4; ++nt)
                acc[mt][nt] = __builtin_amdgcn_mfma_f32_16x16x32_bf16(
                    af[mt], bfr[nt], acc[mt][nt], 0, 0, 0);
        __syncthreads();
    }

    #pragma unroll
    for (int mt = 0; mt < 4; ++mt) {
        #pragma unroll
        for (int r = 0; r < 4; ++r) {
            int row = bm + wm + mt * 16 + quad * 4 + r;
            if (row >= M) continue;
            #pragma unroll
            for (int nt = 0; nt < 4; ++nt) {
                int col = bn + wn + nt * 16 + l15;
                float v = acc[mt][nt][r];
                if (BIAS) v += bias[col];
                if (RELU) v = fmaxf(v, 0.f);
                if (OUTBF) ((bf16_t*)Cv)[(size_t)row * NC + col] = (bf16_t)v;
                else       ((float*)Cv)[(size_t)row * NC + col] = v;
            }
        }
    }

    if (STATS) {
        #pragma unroll
        for (int nt = 0; nt < 4; ++nt) {
            float ps = 0.f, pq = 0.f;
            #pragma unroll
            for (int mt = 0; mt < 4; ++mt)
                #pragma unroll
                for (int r = 0; r < 4; ++r) {
                    int row = bm + wm + mt * 16 + quad * 4 + r;
                    if (row < M) {
                        float v = acc[mt][nt][r];
                        ps += v;
                        pq = fmaf(v, v, pq);
                    }
                }
            ps += __shfl_down(ps, 32, 64); ps += __shfl_down(ps, 16, 64);
            pq += __shfl_down(pq, 32, 64); pq += __shfl_down(pq, 16, 64);
            if (quad == 0) {
                int col = bn + wn + nt * 16 + l15;
                atomicAdd(&s1g[col], ps);
                atomicAdd(&s2g[col], pq);
            }
        }
    }
}

// ---------------- batchnorm ----------------
__global__ __launch_bounds__(256)
void bn_stats_k(const bf16_t* __restrict__ x, float* __restrict__ s1, float* __restrict__ s2)
{
    int c = blockIdx.x * 256 + threadIdx.x;        // < Hc (grid.x = 4)
    int r0 = blockIdx.y * 250;                     // 80 chunks * 250 = 20000
    float s = 0.f, q = 0.f;
    const bf16_t* p = x + (size_t)r0 * Hc + c;
    for (int r = 0; r < 250; ++r) {
        float v = (float)p[(size_t)r * Hc];
        s += v;
        q = fmaf(v, v, q);
    }
    atomicAdd(&s1[c], s);
    atomicAdd(&s2[c], q);
}

__global__ __launch_bounds__(256)
void bn_apply_k(const bf16x8* __restrict__ x8, const float* __restrict__ s1,
                const float* __restrict__ s2, const float* __restrict__ g,
                const float* __restrict__ beta, bf16x8* __restrict__ out8)
{
    int idx = blockIdx.x * 256 + threadIdx.x;      // grid = Nn*Hc/8/256 = 10000
    int c8 = (idx & 127) << 3;
    bf16x8 v = x8[idx];
    bf16x8 o;
    #pragma unroll
    for (int i = 0; i < 8; ++i) {
        int c = c8 + i;
        float mean = s1[c] * (1.0f / Nn);
        float var  = s2[c] * (1.0f / Nn) - mean * mean;
        float sc = g[c] * rsqrtf(var + EPSc);
        float sh = beta[c] - mean * sc;
        o[i] = (bf16_t)fmaxf(fmaf((float)v[i], sc, sh), 0.f);
    }
    out8[idx] = o;
}

// ---------------- head: out = log_softmax(z @ Wl2 + bl2), z in bf16 ----------------
__global__ __launch_bounds__(256)
void head_k(const bf16_t* __restrict__ z, const float* __restrict__ Wl2,
            const float* __restrict__ bl2, float* __restrict__ out)
{
    int wave = threadIdx.x >> 6;
    int lane = threadIdx.x & 63;
    int node = blockIdx.x * 4 + wave;              // grid = Nn/4 exact
    const bf16x4 zv = *(const bf16x4*)(z + (size_t)node * HMc + lane * 4);
    float p[DOUTc];
    #pragma unroll
    for (int j = 0; j < DOUTc; ++j) p[j] = 0.f;
    const float zz[4] = {(float)zv[0], (float)zv[1], (float)zv[2], (float)zv[3]};
    #pragma unroll
    for (int i = 0; i < 4; ++i) {
        int k = lane * 4 + i;
        const float* wrow = Wl2 + (size_t)k * DOUTc;
        #pragma unroll
        for (int j = 0; j < DOUTc; ++j) p[j] = fmaf(zz[i], wrow[j], p[j]);
    }
    #pragma unroll
    for (int j = 0; j < DOUTc; ++j) {
        #pragma unroll
        for (int off = 32; off > 0; off >>= 1) p[j] += __shfl_down(p[j], off, 64);
    }
    if (lane == 0) {
        float v[DOUTc];
        float m = -1e30f;
        #pragma unroll
        for (int j = 0; j < DOUTc; ++j) { v[j] = p[j] + bl2[j]; m = fmaxf(m, v[j]); }
        float s = 0.f;
        #pragma unroll
        for (int j = 0; j < DOUTc; ++j) s += expf(v[j] - m);
        float ls = logf(s) + m;
        #pragma unroll
        for (int j = 0; j < DOUTc; ++j) out[(size_t)node * DOUTc + j] = v[j] - ls;
    }
}

// ---------------- launch ----------------
extern "C" void kernel_launch(void* const* d_in, const int* in_sizes, int n_in,
                              void* d_out, int out_size, void* d_ws, size_t ws_size,
                              hipStream_t stream)
{
    (void)in_sizes; (void)n_in; (void)out_size; (void)ws_size;
    const float* x    = (const float*)d_in[0];
    const int*   ei   = (const int*)d_in[1];
    const float* ew   = (const float*)d_in[2];
    const float* W1   = (const float*)d_in[3];
    // b1 = d_in[4]: cancels under batchnorm mean-subtraction
    const float* gam1 = (const float*)d_in[5];
    const float* bet1 = (const float*)d_in[6];
    const float* W2   = (const float*)d_in[7];
    // b2 = d_in[8]: cancels
    const float* gam2 = (const float*)d_in[9];
    const float* bet2 = (const float*)d_in[10];
    const float* Wl1  = (const float*)d_in[11];
    const float* bl1  = (const float*)d_in[12];
    const float* Wl2  = (const float*)d_in[13];
    const float* bl2  = (const float*)d_in[14];
    float* out = (float*)d_out;

    float* dinv  = (float*)d_ws;                   // Nn
    float* stats = dinv + Nn;                      // 4*Hc: s1a,s2a,s1b,s2b
    float* s1a = stats, *s2a = stats + Hc, *s1b = stats + 2 * Hc, *s2b = stats + 3 * Hc;
    int*   cnt      = (int*)(stats + 4 * Hc);      // Nn
    int*   row_ptr  = cnt + Nn;                    // Nn+16
    int*   cursor   = row_ptr + Nn + 16;           // Nn
    int*   blk      = cursor + Nn;                 // NB_SCAN (+pad)
    int*   csr_src  = blk + 128;                   // Ne
    float* csr_coef = (float*)(csr_src + Ne);      // Ne
    bf16_t* xb    = (bf16_t*)(csr_coef + Ne);      // Nn*DIN  (16B aligned)
    bf16_t* xagg  = xb + (size_t)Nn * DIN;         // Nn*DIN  (aggregated x)
    bf16_t* hgem  = xagg + (size_t)Nn * DIN;       // Nn*Hc   ping
    bf16_t* hbf   = hgem + (size_t)Nn * Hc;        // Nn*Hc   pong
    bf16_t* zhead = hbf + (size_t)Nn * Hc;         // Nn*HMc  (head GEMM out, bf16)
    bf16_t* W1t   = zhead + (size_t)Nn * HMc;      // Hc*DIN  (= W1^T)
    bf16_t* W2t   = W1t + (size_t)Hc * DIN;        // Hc*Hc   (= W2^T)
    bf16_t* Wl1t  = W2t + (size_t)Hc * Hc;         // HMc*Hc  (= Wl1^T)

    const int* srcv = ei;
    const int* dstv = ei + Ne;

    // ---- one-time per launch: dinv + CSR + bf16 weights/x ----
    deg_init_k<<<NB_SCAN, 256, 0, stream>>>(dinv, cnt, stats);
    deg_edge_k<<<(Ne + 255) / 256, 256, 0, stream>>>(ew, dstv, dinv, cnt);
    scanA_k<<<NB_SCAN, 256, 0, stream>>>(cnt, row_ptr, blk, dinv);
    scanB_k<<<1, 128, 0, stream>>>(blk);
    scanC_k<<<NB_SCAN, 256, 0, stream>>>(row_ptr, blk, cursor);
    csr_fill_k<<<(Ne + 255) / 256, 256, 0, stream>>>(srcv, dstv, ew, dinv, cursor,
                                                     csr_src, csr_coef);
    transpose_all_k<<<1408, 256, 0, stream>>>(W1, W2, Wl1, W1t, W2t, Wl1t);
    cvt_bf16_k<<<(Nn * DIN / 4 + 255) / 256, 256, 0, stream>>>(
        (const float4*)x, (bf16x4*)xb, Nn * DIN / 4);

    const int MB = (Nn + 127) / 128;               // 157 row-blocks

    // layer 1:  (A X) W1  — aggregate first (128-dim), then GEMM with fused BN stats
    spmm_x_k<<<4 * ((Nn + 63) / 64), 256, 0, stream>>>(
        (const bf16x8*)xb, row_ptr, csr_src, csr_coef, dinv, (bf16x8*)xagg);
    gemm_bf16_k<Hc, DIN, false, false, true, true><<<dim3(Hc / 128, MB), 256, 0, stream>>>(
        xagg, W1t, nullptr, hgem, Nn, s1a, s2a);
    bn_apply_k<<<Nn * Hc / 8 / 256, 256, 0, stream>>>(
        (const bf16x8*)hgem, s1a, s2a, gam1, bet1, (bf16x8*)hbf);

    // layer 2:  GEMM, aggregate (1024-dim, panel-partitioned), BN
    gemm_bf16_k<Hc, Hc, false, false, true, false><<<dim3(Hc / 128, MB), 256, 0, stream>>>(
        hbf, W2t, nullptr, hgem, Nn, nullptr, nullptr);
    spmm_h_k<<<8 * (Nn / 16), 256, 0, stream>>>(
        (const bf16x8*)hgem, row_ptr, csr_src, csr_coef, dinv, (bf16x8*)hbf);
    bn_stats_k<<<dim3(Hc / 256, 80), 256, 0, stream>>>(hbf, s1b, s2b);
    bn_apply_k<<<Nn * Hc / 8 / 256, 256, 0, stream>>>(
        (const bf16x8*)hbf, s1b, s2b, gam2, bet2, (bf16x8*)hgem);

    // MLP head: z = relu(h @ Wl1 + bl1) (bf16 out), then fused GEMM+log_softmax
    gemm_bf16_k<HMc, Hc, true, true, true, false><<<dim3(HMc / 128, MB), 256, 0, stream>>>(
        hgem, Wl1t, bl1, zhead, Nn, nullptr, nullptr);
    head_k<<<Nn / 4, 256, 0, stream>>>(zhead, Wl2, bl2, out);
}

// Round 14
// 433.267 us; speedup vs baseline: 1.3832x; 1.0066x over previous
//
#include <hip/hip_runtime.h>
#include <math.h>

static constexpr int Nn  = 20000;
static constexpr int Ne  = 320000;
static constexpr int DIN = 128;
static constexpr int DOUTc = 10;
static constexpr int Hc  = 1024;
static constexpr int HMc = 256;
static constexpr float EPSc = 1e-5f;
static constexpr int NB_SCAN = (Nn + 255) / 256;   // 79

typedef __bf16 bf16_t;
typedef __bf16 bf16x8 __attribute__((ext_vector_type(8)));
typedef __bf16 bf16x4 __attribute__((ext_vector_type(4)));
typedef float  f32x4  __attribute__((ext_vector_type(4)));

__device__ __forceinline__ void gload_lds16(const bf16_t* g, bf16_t* lds) {
    __builtin_amdgcn_global_load_lds(
        (const __attribute__((address_space(1))) void*)g,
        (__attribute__((address_space(3))) void*)lds, 16, 0, 0);
}

// ---------------- init: deg=1, cnt=0, stats=0 ----------------
__global__ __launch_bounds__(256)
void deg_init_k(float* __restrict__ deg, int* __restrict__ cnt, float* __restrict__ stats)
{
    int i = blockIdx.x * 256 + threadIdx.x;
    if (i < Nn) { deg[i] = 1.0f; cnt[i] = 0; }     // self-loop weight 1
    if (i < 4 * Hc) stats[i] = 0.f;
}

__global__ __launch_bounds__(256)
void deg_edge_k(const float* __restrict__ w, const int* __restrict__ dstv,
                float* __restrict__ deg, int* __restrict__ cnt) {
    int e = blockIdx.x * 256 + threadIdx.x;
    if (e < Ne) {
        int d = dstv[e];
        atomicAdd(&deg[d], w[e]);
        atomicAdd(&cnt[d], 1);
    }
}

// ---------------- 3-kernel block scan: cnt -> row_ptr/cursor (A finalizes dinv) ----------------
__global__ __launch_bounds__(256)
void scanA_k(const int* __restrict__ cnt, int* __restrict__ row_ptr, int* __restrict__ blk,
             float* __restrict__ deg)
{
    __shared__ int wsum[4];
    int b = blockIdx.x, tid = threadIdx.x, lane = tid & 63, wv = tid >> 6;
    int i = b * 256 + tid;
    if (i < Nn) deg[i] = rsqrtf(deg[i]);           // deg >= 1 always -> dinv
    int v = (i < Nn) ? cnt[i] : 0;
    int s = v;
    #pragma unroll
    for (int off = 1; off < 64; off <<= 1) {
        int t = __shfl_up(s, off, 64);
        if (lane >= off) s += t;
    }
    if (lane == 63) wsum[wv] = s;
    __syncthreads();
    int wo = 0;
    #pragma unroll
    for (int k = 0; k < 4; ++k) if (k < wv) wo += wsum[k];
    if (i < Nn) row_ptr[i] = wo + s - v;           // block-local exclusive
    if (tid == 255) blk[b] = wo + s;               // block total
}

__global__ __launch_bounds__(128)
void scanB_k(int* __restrict__ blk)                // NB_SCAN <= 128
{
    __shared__ int w0;
    int tid = threadIdx.x, lane = tid & 63, wv = tid >> 6;
    int v = (tid < NB_SCAN) ? blk[tid] : 0;
    int s = v;
    #pragma unroll
    for (int off = 1; off < 64; off <<= 1) {
        int t = __shfl_up(s, off, 64);
        if (lane >= off) s += t;
    }
    if (tid == 63) w0 = s;
    __syncthreads();
    int excl = s - v + (wv ? w0 : 0);
    if (tid < NB_SCAN) blk[tid] = excl;
}

__global__ __launch_bounds__(256)
void scanC_k(int* __restrict__ row_ptr, const int* __restrict__ blk, int* __restrict__ cursor)
{
    int b = blockIdx.x;
    int i = b * 256 + threadIdx.x;
    if (i < Nn) {
        int r = row_ptr[i] + blk[b];
        row_ptr[i] = r;
        cursor[i]  = r;
    }
    if (i == 0) row_ptr[Nn] = Ne;
}

// ---------------- CSR fill (coeff precomputed) ----------------
__global__ __launch_bounds__(256)
void csr_fill_k(const int* __restrict__ srcv, const int* __restrict__ dstv,
                const float* __restrict__ w, const float* __restrict__ dinv,
                int* __restrict__ cursor, int* __restrict__ csr_src,
                float* __restrict__ csr_coeff)
{
    int e = blockIdx.x * 256 + threadIdx.x;
    if (e >= Ne) return;
    int s = srcv[e], d = dstv[e];
    int pos = atomicAdd(&cursor[d], 1);
    csr_src[pos]   = s;
    csr_coeff[pos] = dinv[s] * w[e] * dinv[d];
}

// ---------------- gather SpMM over x (128-dim), panel + 4x unrolled ----------------
__global__ __launch_bounds__(256)
void spmm_x_k(const bf16x8* __restrict__ x8, const int* __restrict__ row_ptr,
              const int* __restrict__ csr_src, const float* __restrict__ csr_coeff,
              const float* __restrict__ dinv, bf16x8* __restrict__ out8)
{
    int panel = blockIdx.x & 3;
    int node  = (blockIdx.x >> 2) * 64 + (threadIdx.x >> 2);
    if (node >= Nn) return;
    int f = (threadIdx.x & 3) + panel * 4;
    float c = dinv[node]; c = c * c;
    bf16x8 hv = x8[(size_t)node * 16 + f];
    float acc[8];
    #pragma unroll
    for (int i = 0; i < 8; ++i) acc[i] = c * (float)hv[i];
    int beg = row_ptr[node], end = row_ptr[node + 1];
    int j = beg;
    for (; j + 4 <= end; j += 4) {
        int   s0 = csr_src[j + 0], s1 = csr_src[j + 1];
        int   s2 = csr_src[j + 2], s3 = csr_src[j + 3];
        float c0 = csr_coeff[j + 0], c1 = csr_coeff[j + 1];
        float c2 = csr_coeff[j + 2], c3 = csr_coeff[j + 3];
        bf16x8 v0 = x8[(size_t)s0 * 16 + f];
        bf16x8 v1 = x8[(size_t)s1 * 16 + f];
        bf16x8 v2 = x8[(size_t)s2 * 16 + f];
        bf16x8 v3 = x8[(size_t)s3 * 16 + f];
        #pragma unroll
        for (int i = 0; i < 8; ++i) {
            acc[i] = fmaf(c0, (float)v0[i], acc[i]);
            acc[i] = fmaf(c1, (float)v1[i], acc[i]);
            acc[i] = fmaf(c2, (float)v2[i], acc[i]);
            acc[i] = fmaf(c3, (float)v3[i], acc[i]);
        }
    }
    for (; j < end; ++j) {
        int   s  = csr_src[j];
        float cf = csr_coeff[j];
        bf16x8 v = x8[(size_t)s * 16 + f];
        #pragma unroll
        for (int i = 0; i < 8; ++i) acc[i] = fmaf(cf, (float)v[i], acc[i]);
    }
    bf16x8 o;
    #pragma unroll
    for (int i = 0; i < 8; ++i) o[i] = (bf16_t)acc[i];
    out8[(size_t)node * 16 + f] = o;
}

// ---------------- gather SpMM over h (1024-dim), panel + clean 8x unroll ----------------
// 8 panels x 128 feats; 16 nodes/block, 16 lanes/node. No stats fusion, no LDS
// (round-12 lesson: those cost occupancy). 8 independent gathers in flight.
__global__ __launch_bounds__(256)
void spmm_h_k(const bf16x8* __restrict__ h8, const int* __restrict__ row_ptr,
              const int* __restrict__ csr_src, const float* __restrict__ csr_coeff,
              const float* __restrict__ dinv, bf16x8* __restrict__ out8)
{
    int panel = blockIdx.x & 7;
    int node  = (blockIdx.x >> 3) * 16 + (threadIdx.x >> 4);   // grid = 8*1250 exact
    int f     = (threadIdx.x & 15) + panel * 16;
    float c = dinv[node]; c = c * c;
    bf16x8 hv = h8[(size_t)node * 128 + f];
    float acc[8];
    #pragma unroll
    for (int i = 0; i < 8; ++i) acc[i] = c * (float)hv[i];
    int beg = row_ptr[node], end = row_ptr[node + 1];
    int j = beg;
    for (; j + 8 <= end; j += 8) {
        int   s0 = csr_src[j + 0], s1 = csr_src[j + 1];
        int   s2 = csr_src[j + 2], s3 = csr_src[j + 3];
        int   s4 = csr_src[j + 4], s5 = csr_src[j + 5];
        int   s6 = csr_src[j + 6], s7 = csr_src[j + 7];
        float c0 = csr_coeff[j + 0], c1 = csr_coeff[j + 1];
        float c2 = csr_coeff[j + 2], c3 = csr_coeff[j + 3];
        float c4 = csr_coeff[j + 4], c5 = csr_coeff[j + 5];
        float c6 = csr_coeff[j + 6], c7 = csr_coeff[j + 7];
        bf16x8 v0 = h8[(size_t)s0 * 128 + f];
        bf16x8 v1 = h8[(size_t)s1 * 128 + f];
        bf16x8 v2 = h8[(size_t)s2 * 128 + f];
        bf16x8 v3 = h8[(size_t)s3 * 128 + f];
        bf16x8 v4 = h8[(size_t)s4 * 128 + f];
        bf16x8 v5 = h8[(size_t)s5 * 128 + f];
        bf16x8 v6 = h8[(size_t)s6 * 128 + f];
        bf16x8 v7 = h8[(size_t)s7 * 128 + f];
        #pragma unroll
        for (int i = 0; i < 8; ++i) {
            acc[i] = fmaf(c0, (float)v0[i], acc[i]);
            acc[i] = fmaf(c1, (float)v1[i], acc[i]);
            acc[i] = fmaf(c2, (float)v2[i], acc[i]);
            acc[i] = fmaf(c3, (float)v3[i], acc[i]);
            acc[i] = fmaf(c4, (float)v4[i], acc[i]);
            acc[i] = fmaf(c5, (float)v5[i], acc[i]);
            acc[i] = fmaf(c6, (float)v6[i], acc[i]);
            acc[i] = fmaf(c7, (float)v7[i], acc[i]);
        }
    }
    for (; j + 4 <= end; j += 4) {
        int   s0 = csr_src[j + 0], s1 = csr_src[j + 1];
        int   s2 = csr_src[j + 2], s3 = csr_src[j + 3];
        float c0 = csr_coeff[j + 0], c1 = csr_coeff[j + 1];
        float c2 = csr_coeff[j + 2], c3 = csr_coeff[j + 3];
        bf16x8 v0 = h8[(size_t)s0 * 128 + f];
        bf16x8 v1 = h8[(size_t)s1 * 128 + f];
        bf16x8 v2 = h8[(size_t)s2 * 128 + f];
        bf16x8 v3 = h8[(size_t)s3 * 128 + f];
        #pragma unroll
        for (int i = 0; i < 8; ++i) {
            acc[i] = fmaf(c0, (float)v0[i], acc[i]);
            acc[i] = fmaf(c1, (float)v1[i], acc[i]);
            acc[i] = fmaf(c2, (float)v2[i], acc[i]);
            acc[i] = fmaf(c3, (float)v3[i], acc[i]);
        }
    }
    for (; j < end; ++j) {
        int   s  = csr_src[j];
        float cf = csr_coeff[j];
        bf16x8 v = h8[(size_t)s * 128 + f];
        #pragma unroll
        for (int i = 0; i < 8; ++i) acc[i] = fmaf(cf, (float)v[i], acc[i]);
    }
    bf16x8 o;
    #pragma unroll
    for (int i = 0; i < 8; ++i) o[i] = (bf16_t)acc[i];
    out8[(size_t)node * 128 + f] = o;
}

// ---------------- merged: weight transposes (3 matrices) + x fp32->bf16 convert ----------------
__global__ __launch_bounds__(256)
void prep_all_k(const float* __restrict__ W1, const float* __restrict__ W2,
                const float* __restrict__ Wl1, bf16_t* __restrict__ W1t,
                bf16_t* __restrict__ W2t, bf16_t* __restrict__ Wl1t,
                const float4* __restrict__ xin, bf16x4* __restrict__ xout)
{
    int b = blockIdx.x;
    if (b >= 1408) {                               // x convert: 2500 blocks
        int i = (b - 1408) * 256 + threadIdx.x;
        if (i < Nn * DIN / 4) {
            float4 v = xin[i];
            bf16x4 o = { (bf16_t)v.x, (bf16_t)v.y, (bf16_t)v.z, (bf16_t)v.w };
            xout[i] = o;
        }
        return;
    }
    __shared__ float tile[32][33];
    const float* W; bf16_t* Wt; int R, C, bx, by;
    if (b < 128)       { W = W1;  Wt = W1t;  R = DIN; C = Hc;  int t = b;        bx = (t & 31) * 32; by = (t >> 5) * 32; }
    else if (b < 1152) { W = W2;  Wt = W2t;  R = Hc;  C = Hc;  int t = b - 128;  bx = (t & 31) * 32; by = (t >> 5) * 32; }
    else               { W = Wl1; Wt = Wl1t; R = Hc;  C = HMc; int t = b - 1152; bx = (t & 7) * 32;  by = (t >> 3) * 32; }
    int tx = threadIdx.x & 31, ty = threadIdx.x >> 5;  // ty 0..7
    #pragma unroll
    for (int p = 0; p < 32; p += 8)
        tile[ty + p][tx] = W[(size_t)(by + ty + p) * C + bx + tx];
    __syncthreads();
    #pragma unroll
    for (int p = 0; p < 32; p += 8)
        Wt[(size_t)(bx + ty + p) * R + by + tx] = (bf16_t)tile[tx][ty + p];
}

// ---------------- bf16 MFMA GEMM: C[M x NC] = A[M x KD] @ Bt[NC x KD]^T ----------------
template<int NC, int KD, bool BIAS, bool RELU, bool OUTBF, bool STATS>
__global__ __launch_bounds__(256)
void gemm_bf16_k(const bf16_t* __restrict__ A, const bf16_t* __restrict__ Bt,
                 const float* __restrict__ bias, void* __restrict__ Cv, int M,
                 float* __restrict__ s1g, float* __restrict__ s2g)
{
    __shared__ __align__(16) bf16_t Asm[128 * 32];
    __shared__ __align__(16) bf16_t Bsm[128 * 32];
    const int tid  = threadIdx.x;
    const int w    = tid >> 6;
    const int lane = tid & 63;
    const int bm = blockIdx.y * 128, bn = blockIdx.x * 128;
    const int l15 = lane & 15, quad = lane >> 4;
    const int wm = (w & 1) * 64, wn = (w >> 1) * 64;
    const int swz = quad ^ ((l15 >> 1) & 3);

    const int srow = lane >> 2;
    const int scol = 8 * ((lane & 3) ^ ((lane >> 3) & 3));
    const int c0 = w * 32;
    int ga0 = bm + c0 + srow;       if (ga0 >= M) ga0 = M - 1;
    int ga1 = bm + c0 + 16 + srow;  if (ga1 >= M) ga1 = M - 1;
    const bf16_t* gA0 = A + (size_t)ga0 * KD + scol;
    const bf16_t* gA1 = A + (size_t)ga1 * KD + scol;
    const bf16_t* gB0 = Bt + (size_t)(bn + c0 + srow) * KD + scol;
    const bf16_t* gB1 = gB0 + (size_t)16 * KD;
    bf16_t* lA0 = Asm + (c0 +  0) * 32;
    bf16_t* lA1 = Asm + (c0 + 16) * 32;
    bf16_t* lB0 = Bsm + (c0 +  0) * 32;
    bf16_t* lB1 = Bsm + (c0 + 16) * 32;

    const bf16_t* pA = Asm + (wm + l15) * 32 + swz * 8;
    const bf16_t* pB = Bsm + (wn + l15) * 32 + swz * 8;

    f32x4 acc[4][4] = {};

    for (int k0 = 0; k0 < KD; k0 += 32) {
        gload_lds16(gA0 + k0, lA0);
        gload_lds16(gA1 + k0, lA1);
        gload_lds16(gB0 + k0, lB0);
        gload_lds16(gB1 + k0, lB1);
        __syncthreads();
        bf16x8 af[4], bfr[4];
        #pragma unroll
        for (int t = 0; t < 4; ++t) {
            af[t]  = *(const bf16x8*)(pA + t * 16 * 32);
            bfr[t] = *(const bf16x8*)(pB + t * 16 * 32);
        }
        #pragma unroll
        for (int mt = 0; mt < 4; ++mt)
            #pragma unroll
            for (int nt = 0; nt < 4; ++nt)
                acc[mt][nt] = __builtin_amdgcn_mfma_f32_16x16x32_bf16(
                    af[mt], bfr[nt], acc[mt][nt], 0, 0, 0);
        __syncthreads();
    }

    #pragma unroll
    for (int mt = 0; mt < 4; ++mt) {
        #pragma unroll
        for (int r = 0; r < 4; ++r) {
            int row = bm + wm + mt * 16 + quad * 4 + r;
            if (row >= M) continue;
            #pragma unroll
            for (int nt = 0; nt < 4; ++nt) {
                int col = bn + wn + nt * 16 + l15;
                float v = acc[mt][nt][r];
                if (BIAS) v += bias[col];
                if (RELU) v = fmaxf(v, 0.f);
                if (OUTBF) ((bf16_t*)Cv)[(size_t)row * NC + col] = (bf16_t)v;
                else       ((float*)Cv)[(size_t)row * NC + col] = v;
            }
        }
    }

    if (STATS) {
        #pragma unroll
        for (int nt = 0; nt < 4; ++nt) {
            float ps = 0.f, pq = 0.f;
            #pragma unroll
            for (int mt = 0; mt < 4; ++mt)
                #pragma unroll
                for (int r = 0; r < 4; ++r) {
                    int row = bm + wm + mt * 16 + quad * 4 + r;
                    if (row < M) {
                        float v = acc[mt][nt][r];
                        ps += v;
                        pq = fmaf(v, v, pq);
                    }
                }
            ps += __shfl_down(ps, 32, 64); ps += __shfl_down(ps, 16, 64);
            pq += __shfl_down(pq, 32, 64); pq += __shfl_down(pq, 16, 64);
            if (quad == 0) {
                int col = bn + wn + nt * 16 + l15;
                atomicAdd(&s1g[col], ps);
                atomicAdd(&s2g[col], pq);
            }
        }
    }
}

// ---------------- batchnorm ----------------
__global__ __launch_bounds__(256)
void bn_stats_k(const bf16_t* __restrict__ x, float* __restrict__ s1, float* __restrict__ s2)
{
    int c = blockIdx.x * 256 + threadIdx.x;        // < Hc (grid.x = 4)
    int r0 = blockIdx.y * 250;                     // 80 chunks * 250 = 20000
    float s = 0.f, q = 0.f;
    const bf16_t* p = x + (size_t)r0 * Hc + c;
    for (int r = 0; r < 250; ++r) {
        float v = (float)p[(size_t)r * Hc];
        s += v;
        q = fmaf(v, v, q);
    }
    atomicAdd(&s1[c], s);
    atomicAdd(&s2[c], q);
}

__global__ __launch_bounds__(256)
void bn_apply_k(const bf16x8* __restrict__ x8, const float* __restrict__ s1,
                const float* __restrict__ s2, const float* __restrict__ g,
                const float* __restrict__ beta, bf16x8* __restrict__ out8)
{
    int idx = blockIdx.x * 256 + threadIdx.x;      // grid = Nn*Hc/8/256 = 10000
    int c8 = (idx & 127) << 3;
    bf16x8 v = x8[idx];
    bf16x8 o;
    #pragma unroll
    for (int i = 0; i < 8; ++i) {
        int c = c8 + i;
        float mean = s1[c] * (1.0f / Nn);
        float var  = s2[c] * (1.0f / Nn) - mean * mean;
        float sc = g[c] * rsqrtf(var + EPSc);
        float sh = beta[c] - mean * sc;
        o[i] = (bf16_t)fmaxf(fmaf((float)v[i], sc, sh), 0.f);
    }
    out8[idx] = o;
}

// ---------------- head: out = log_softmax(z @ Wl2 + bl2), z in bf16 ----------------
__global__ __launch_bounds__(256)
void head_k(const bf16_t* __restrict__ z, const float* __restrict__ Wl2,
            const float* __restrict__ bl2, float* __restrict__ out)
{
    int wave = threadIdx.x >> 6;
    int lane = threadIdx.x & 63;
    int node = blockIdx.x * 4 + wave;              // grid = Nn/4 exact
    const bf16x4 zv = *(const bf16x4*)(z + (size_t)node * HMc + lane * 4);
    float p[DOUTc];
    #pragma unroll
    for (int j = 0; j < DOUTc; ++j) p[j] = 0.f;
    const float zz[4] = {(float)zv[0], (float)zv[1], (float)zv[2], (float)zv[3]};
    #pragma unroll
    for (int i = 0; i < 4; ++i) {
        int k = lane * 4 + i;
        const float* wrow = Wl2 + (size_t)k * DOUTc;
        #pragma unroll
        for (int j = 0; j < DOUTc; ++j) p[j] = fmaf(zz[i], wrow[j], p[j]);
    }
    #pragma unroll
    for (int j = 0; j < DOUTc; ++j) {
        #pragma unroll
        for (int off = 32; off > 0; off >>= 1) p[j] += __shfl_down(p[j], off, 64);
    }
    if (lane == 0) {
        float v[DOUTc];
        float m = -1e30f;
        #pragma unroll
        for (int j = 0; j < DOUTc; ++j) { v[j] = p[j] + bl2[j]; m = fmaxf(m, v[j]); }
        float s = 0.f;
        #pragma unroll
        for (int j = 0; j < DOUTc; ++j) s += expf(v[j] - m);
        float ls = logf(s) + m;
        #pragma unroll
        for (int j = 0; j < DOUTc; ++j) out[(size_t)node * DOUTc + j] = v[j] - ls;
    }
}

// ---------------- launch ----------------
extern "C" void kernel_launch(void* const* d_in, const int* in_sizes, int n_in,
                              void* d_out, int out_size, void* d_ws, size_t ws_size,
                              hipStream_t stream)
{
    (void)in_sizes; (void)n_in; (void)out_size; (void)ws_size;
    const float* x    = (const float*)d_in[0];
    const int*   ei   = (const int*)d_in[1];
    const float* ew   = (const float*)d_in[2];
    const float* W1   = (const float*)d_in[3];
    // b1 = d_in[4]: cancels under batchnorm mean-subtraction
    const float* gam1 = (const float*)d_in[5];
    const float* bet1 = (const float*)d_in[6];
    const float* W2   = (const float*)d_in[7];
    // b2 = d_in[8]: cancels
    const float* gam2 = (const float*)d_in[9];
    const float* bet2 = (const float*)d_in[10];
    const float* Wl1  = (const float*)d_in[11];
    const float* bl1  = (const float*)d_in[12];
    const float* Wl2  = (const float*)d_in[13];
    const float* bl2  = (const float*)d_in[14];
    float* out = (float*)d_out;

    float* dinv  = (float*)d_ws;                   // Nn
    float* stats = dinv + Nn;                      // 4*Hc: s1a,s2a,s1b,s2b
    float* s1a = stats, *s2a = stats + Hc, *s1b = stats + 2 * Hc, *s2b = stats + 3 * Hc;
    int*   cnt      = (int*)(stats + 4 * Hc);      // Nn
    int*   row_ptr  = cnt + Nn;                    // Nn+16
    int*   cursor   = row_ptr + Nn + 16;           // Nn
    int*   blk      = cursor + Nn;                 // NB_SCAN (+pad)
    int*   csr_src  = blk + 128;                   // Ne
    float* csr_coef = (float*)(csr_src + Ne);      // Ne
    bf16_t* xb    = (bf16_t*)(csr_coef + Ne);      // Nn*DIN  (16B aligned)
    bf16_t* xagg  = xb + (size_t)Nn * DIN;         // Nn*DIN  (aggregated x)
    bf16_t* hgem  = xagg + (size_t)Nn * DIN;       // Nn*Hc   ping
    bf16_t* hbf   = hgem + (size_t)Nn * Hc;        // Nn*Hc   pong
    bf16_t* zhead = hbf + (size_t)Nn * Hc;         // Nn*HMc  (head GEMM out, bf16)
    bf16_t* W1t   = zhead + (size_t)Nn * HMc;      // Hc*DIN  (= W1^T)
    bf16_t* W2t   = W1t + (size_t)Hc * DIN;        // Hc*Hc   (= W2^T)
    bf16_t* Wl1t  = W2t + (size_t)Hc * Hc;         // HMc*Hc  (= Wl1^T)

    const int* srcv = ei;
    const int* dstv = ei + Ne;

    // ---- one-time per launch: dinv + CSR + bf16 weights/x ----
    deg_init_k<<<NB_SCAN, 256, 0, stream>>>(dinv, cnt, stats);
    deg_edge_k<<<(Ne + 255) / 256, 256, 0, stream>>>(ew, dstv, dinv, cnt);
    scanA_k<<<NB_SCAN, 256, 0, stream>>>(cnt, row_ptr, blk, dinv);
    scanB_k<<<1, 128, 0, stream>>>(blk);
    scanC_k<<<NB_SCAN, 256, 0, stream>>>(row_ptr, blk, cursor);
    csr_fill_k<<<(Ne + 255) / 256, 256, 0, stream>>>(srcv, dstv, ew, dinv, cursor,
                                                     csr_src, csr_coef);
    prep_all_k<<<1408 + (Nn * DIN / 4 + 255) / 256, 256, 0, stream>>>(
        W1, W2, Wl1, W1t, W2t, Wl1t, (const float4*)x, (bf16x4*)xb);

    const int MB = (Nn + 127) / 128;               // 157 row-blocks

    // layer 1:  (A X) W1  — aggregate first (128-dim), then GEMM with fused BN stats
    spmm_x_k<<<4 * ((Nn + 63) / 64), 256, 0, stream>>>(
        (const bf16x8*)xb, row_ptr, csr_src, csr_coef, dinv, (bf16x8*)xagg);
    gemm_bf16_k<Hc, DIN, false, false, true, true><<<dim3(Hc / 128, MB), 256, 0, stream>>>(
        xagg, W1t, nullptr, hgem, Nn, s1a, s2a);
    bn_apply_k<<<Nn * Hc / 8 / 256, 256, 0, stream>>>(
        (const bf16x8*)hgem, s1a, s2a, gam1, bet1, (bf16x8*)hbf);

    // layer 2:  GEMM, aggregate (1024-dim, panel-partitioned), BN
    gemm_bf16_k<Hc, Hc, false, false, true, false><<<dim3(Hc / 128, MB), 256, 0, stream>>>(
        hbf, W2t, nullptr, hgem, Nn, nullptr, nullptr);
    spmm_h_k<<<8 * (Nn / 16), 256, 0, stream>>>(
        (const bf16x8*)hgem, row_ptr, csr_src, csr_coef, dinv, (bf16x8*)hbf);
    bn_stats_k<<<dim3(Hc / 256, 80), 256, 0, stream>>>(hbf, s1b, s2b);
    bn_apply_k<<<Nn * Hc / 8 / 256, 256, 0, stream>>>(
        (const bf16x8*)hbf, s1b, s2b, gam2, bet2, (bf16x8*)hgem);

    // MLP head: z = relu(h @ Wl1 + bl1) (bf16 out), then fused GEMM+log_softmax
    gemm_bf16_k<HMc, Hc, true, true, true, false><<<dim3(HMc / 128, MB), 256, 0, stream>>>(
        hgem, Wl1t, bl1, zhead, Nn, nullptr, nullptr);
    head_k<<<Nn / 4, 256, 0, stream>>>(zhead, Wl2, bl2, out);
}